// Round 2
// baseline (341.106 us; speedup 1.0000x reference)
//
#include <hip/hip_runtime.h>

// Problem constants (fixed by setup_inputs): B=4, N_TOK=16384, DIM=256,
// NH=8, NP=4, HD=32, H=W=128.  M = B*N_TOK = 65536 rows.

typedef __attribute__((ext_vector_type(8))) short bf16x8;
typedef __attribute__((ext_vector_type(4))) float f32x4;

__device__ __forceinline__ short f2bf(float f) {
  unsigned u = __float_as_uint(f);
  u = u + 0x7FFFu + ((u >> 16) & 1u);   // round-to-nearest-even
  return (short)(u >> 16);
}
__device__ __forceinline__ float bf2f(short s) {
  return __uint_as_float(((unsigned)(unsigned short)s) << 16);
}

// ---------------------------------------------------------------- k_prep
// wcat[384][256] bf16 = concat(v_w[256], aw_w[32], off_w[64], zeros[32])
// wproj[256][256] bf16 = proj_w
__global__ __launch_bounds__(256) void k_prep(
    const float* __restrict__ v_w, const float* __restrict__ aw_w,
    const float* __restrict__ off_w, const float* __restrict__ proj_w,
    short* __restrict__ wcat, short* __restrict__ wproj)
{
  int idx = blockIdx.x * 256 + threadIdx.x;   // grid 640 -> idx < 163840
  if (idx < 384 * 256) {
    int row = idx >> 8;
    float val = 0.f;
    if (row < 256)      val = v_w[idx];
    else if (row < 288) val = aw_w[idx - 256 * 256];
    else if (row < 352) val = off_w[idx - 288 * 256];
    wcat[idx] = f2bf(val);
  } else {
    int j = idx - 384 * 256;                  // < 65536
    wproj[j] = f2bf(proj_w[j]);
  }
}

// ---------------------------------------------------------------- k_proj
// C[65536][384] = x @ wcat.T ; epilogue scatters v / aw / off.
// Tile 64x64, 4 waves (2x2 of 32x32), K=256 in one LDS stage.
// LDS layout: 16B groups XOR-swizzled by row to avoid 16-way bank conflicts.
__global__ __launch_bounds__(256) void k_proj(
    const float* __restrict__ x, const short* __restrict__ wcat,
    const float* __restrict__ v_b, const float* __restrict__ aw_b,
    const float* __restrict__ off_b,
    float* __restrict__ vbuf,            // [32][16384][32] f32 (= d_out scratch)
    float* __restrict__ awraw,           // [32][16384][4]
    float* __restrict__ offraw)          // [32][16384][4][2]
{
  __shared__ short xs[64 * 256];
  __shared__ short wsm[64 * 256];
  const int tid  = threadIdx.x;
  const int c0   = blockIdx.x << 6;   // col tile fastest-varying -> x-tile L2 reuse
  const int row0 = blockIdx.y << 6;

  {
    const float* xg = x + (size_t)row0 * 256;
    const short* wg = wcat + (size_t)c0 * 256;
#pragma unroll
    for (int i = 0; i < 8; i++) {
      int G = i * 256 + tid;             // 16B group index within 64x256 tile
      int row = G >> 5, gcol = G & 31;
      int Gs = (row << 5) + (gcol ^ (row & 7));   // swizzled group
      const f32x4* src = (const f32x4*)(xg + (size_t)G * 8);
      f32x4 f0 = src[0], f1 = src[1];
      bf16x8 v;
      v[0] = f2bf(f0[0]); v[1] = f2bf(f0[1]); v[2] = f2bf(f0[2]); v[3] = f2bf(f0[3]);
      v[4] = f2bf(f1[0]); v[5] = f2bf(f1[1]); v[6] = f2bf(f1[2]); v[7] = f2bf(f1[3]);
      *(bf16x8*)&xs[Gs * 8] = v;
      *(bf16x8*)&wsm[Gs * 8] = *(const bf16x8*)(wg + (size_t)G * 8);
    }
  }
  __syncthreads();

  const int wave = tid >> 6, lane = tid & 63;
  const int wr = wave >> 1, wc = wave & 1;
  const int lr = lane & 15;
  const int kg = lane >> 4;            // k-group 0..3 (8 elems each)
  f32x4 acc[2][2] = {};

#pragma unroll
  for (int ks = 0; ks < 8; ks++) {
    bf16x8 a[2], b[2];
#pragma unroll
    for (int m = 0; m < 2; m++) {
      int row = (wr << 5) + (m << 4) + lr;
      int g = (ks << 2) + kg;
      a[m] = *(const bf16x8*)&xs[(row << 8) + ((g ^ (row & 7)) << 3)];
    }
#pragma unroll
    for (int n = 0; n < 2; n++) {
      int row = (wc << 5) + (n << 4) + lr;
      int g = (ks << 2) + kg;
      b[n] = *(const bf16x8*)&wsm[(row << 8) + ((g ^ (row & 7)) << 3)];
    }
#pragma unroll
    for (int m = 0; m < 2; m++)
#pragma unroll
      for (int n = 0; n < 2; n++)
        acc[m][n] = __builtin_amdgcn_mfma_f32_16x16x32_bf16(a[m], b[n], acc[m][n], 0, 0, 0);
  }

  // epilogue: C/D layout col=lane&15, row=(lane>>4)*4+reg  [m89-verified]
#pragma unroll
  for (int m = 0; m < 2; m++) {
#pragma unroll
    for (int n = 0; n < 2; n++) {
#pragma unroll
      for (int j = 0; j < 4; j++) {
        int r = row0 + (wr << 5) + (m << 4) + ((lane >> 4) << 2) + j;
        int c = c0 + (wc << 5) + (n << 4) + (lane & 15);
        float v = acc[m][n][j];
        int b_ = r >> 14, nn = r & 16383;
        if (c < 256) {
          float val = v + v_b[c];
          int h = c >> 5, d = c & 31;
          vbuf[((((size_t)((b_ << 3) + h)) << 14) + nn) * 32 + d] = val;
        } else if (c < 288) {
          int q = c - 256;
          int h = q >> 2, p = q & 3;
          awraw[((((size_t)((b_ << 3) + h)) << 14) + nn) * 4 + p] = v + aw_b[q];
        } else if (c < 352) {
          int q = c - 288;
          int h = q >> 3, rest = q & 7;   // rest = p*2 + xy
          offraw[((((size_t)((b_ << 3) + h)) << 14) + nn) * 8 + rest] = v + off_b[q];
        } // c >= 352: padding, skip
      }
    }
  }
}

// ---------------------------------------------------------------- k_sample
// 32 lanes per (g,n) item; softmax over 4 points; bilinear gather (zero pad).
__global__ __launch_bounds__(256) void k_sample(
    const float* __restrict__ vbuf, const float* __restrict__ awraw,
    const float* __restrict__ offraw, unsigned short* __restrict__ attn)
{
  const int tid = threadIdx.x;
  const int item = (blockIdx.x << 3) + (tid >> 5);   // g*16384 + n
  const int d = tid & 31;
  const int g = item >> 14, n = item & 16383;
  const float px = (float)(n & 127), py = (float)(n >> 7);

  const float* ap = awraw + (size_t)item * 4;
  const float* op = offraw + (size_t)item * 8;
  float a0 = ap[0], a1 = ap[1], a2 = ap[2], a3 = ap[3];
  float mx = fmaxf(fmaxf(a0, a1), fmaxf(a2, a3));
  float e0 = expf(a0 - mx), e1 = expf(a1 - mx), e2 = expf(a2 - mx), e3 = expf(a3 - mx);
  float inv = 1.f / (e0 + e1 + e2 + e3);

  const float* vg = vbuf + ((((size_t)g) << 14) << 5);
  float wt[4] = {e0 * inv, e1 * inv, e2 * inv, e3 * inv};
  float o = 0.f;
#pragma unroll
  for (int p = 0; p < 4; p++) {
    float gx = px + op[2 * p], gy = py + op[2 * p + 1];
    float x0f = floorf(gx), y0f = floorf(gy);
    float wx1 = gx - x0f, wx0 = 1.f - wx1;
    float wy1 = gy - y0f, wy0 = 1.f - wy1;
    int x0 = (int)x0f, y0 = (int)y0f;
    float c00 = 0.f, c10 = 0.f, c01 = 0.f, c11 = 0.f;
    if ((unsigned)x0 < 128u && (unsigned)y0 < 128u)
      c00 = vg[(((y0 << 7) + x0) << 5) + d];
    if ((unsigned)(x0 + 1) < 128u && (unsigned)y0 < 128u)
      c10 = vg[(((y0 << 7) + x0 + 1) << 5) + d];
    if ((unsigned)x0 < 128u && (unsigned)(y0 + 1) < 128u)
      c01 = vg[((((y0 + 1) << 7) + x0) << 5) + d];
    if ((unsigned)(x0 + 1) < 128u && (unsigned)(y0 + 1) < 128u)
      c11 = vg[((((y0 + 1) << 7) + x0 + 1) << 5) + d];
    float s = wy0 * (wx0 * c00 + wx1 * c10) + wy1 * (wx0 * c01 + wx1 * c11);
    o += wt[p] * s;
  }
  int b_ = g >> 3, h = g & 7;
  attn[((((size_t)b_ << 14) + n) << 8) + (h << 5) + d] = (unsigned short)f2bf(o);
}

// ---------------------------------------------------------------- k_out
// out[65536][256] = attn @ proj_w.T + proj_b   (f32 output)
__global__ __launch_bounds__(256) void k_out(
    const unsigned short* __restrict__ attn, const short* __restrict__ wproj,
    const float* __restrict__ proj_b, float* __restrict__ out)
{
  __shared__ short xs[64 * 256];
  __shared__ short wsm[64 * 256];
  const int tid  = threadIdx.x;
  const int c0   = blockIdx.x << 6;
  const int row0 = blockIdx.y << 6;
  {
    const short* ag = (const short*)attn + (size_t)row0 * 256;
    const short* wg = wproj + (size_t)c0 * 256;
#pragma unroll
    for (int i = 0; i < 8; i++) {
      int G = i * 256 + tid;
      int row = G >> 5, gcol = G & 31;
      int Gs = (row << 5) + (gcol ^ (row & 7));
      *(bf16x8*)&xs[Gs * 8]  = *(const bf16x8*)(ag + (size_t)G * 8);
      *(bf16x8*)&wsm[Gs * 8] = *(const bf16x8*)(wg + (size_t)G * 8);
    }
  }
  __syncthreads();

  const int wave = tid >> 6, lane = tid & 63;
  const int wr = wave >> 1, wc = wave & 1;
  const int lr = lane & 15;
  const int kg = lane >> 4;
  f32x4 acc[2][2] = {};

#pragma unroll
  for (int ks = 0; ks < 8; ks++) {
    bf16x8 a[2], b[2];
#pragma unroll
    for (int m = 0; m < 2; m++) {
      int row = (wr << 5) + (m << 4) + lr;
      int g = (ks << 2) + kg;
      a[m] = *(const bf16x8*)&xs[(row << 8) + ((g ^ (row & 7)) << 3)];
    }
#pragma unroll
    for (int n = 0; n < 2; n++) {
      int row = (wc << 5) + (n << 4) + lr;
      int g = (ks << 2) + kg;
      b[n] = *(const bf16x8*)&wsm[(row << 8) + ((g ^ (row & 7)) << 3)];
    }
#pragma unroll
    for (int m = 0; m < 2; m++)
#pragma unroll
      for (int n = 0; n < 2; n++)
        acc[m][n] = __builtin_amdgcn_mfma_f32_16x16x32_bf16(a[m], b[n], acc[m][n], 0, 0, 0);
  }

#pragma unroll
  for (int m = 0; m < 2; m++) {
#pragma unroll
    for (int n = 0; n < 2; n++) {
#pragma unroll
      for (int j = 0; j < 4; j++) {
        int r = row0 + (wr << 5) + (m << 4) + ((lane >> 4) << 2) + j;
        int c = c0 + (wc << 5) + (n << 4) + (lane & 15);
        out[(size_t)r * 256 + c] = acc[m][n][j] + proj_b[c];
      }
    }
  }
}

// ---------------------------------------------------------------- launch
extern "C" void kernel_launch(void* const* d_in, const int* in_sizes, int n_in,
                              void* d_out, int out_size, void* d_ws, size_t ws_size,
                              hipStream_t stream)
{
  const float* x      = (const float*)d_in[0];
  const float* v_w    = (const float*)d_in[1];
  const float* v_b    = (const float*)d_in[2];
  const float* aw_w   = (const float*)d_in[3];
  const float* aw_b   = (const float*)d_in[4];
  const float* off_w  = (const float*)d_in[5];
  const float* off_b  = (const float*)d_in[6];
  const float* proj_w = (const float*)d_in[7];
  const float* proj_b = (const float*)d_in[8];
  float* out = (float*)d_out;

  char* ws = (char*)d_ws;
  short* wcat   = (short*)(ws + 0);               // 196,608 B
  short* wproj  = (short*)(ws + 262144);          // 131,072 B
  float* awraw  = (float*)(ws + 1048576);         // 8,388,608 B
  float* offraw = (float*)(ws + 9437184);         // 16,777,216 B
  unsigned short* attn = (unsigned short*)(ws + 26214400);  // 33,554,432 B
  float* vbuf = (float*)d_out;  // reuse d_out (64MB) as f32 v maps (exactly 64MB)

  hipLaunchKernelGGL(k_prep,   dim3(640),      dim3(256), 0, stream,
                     v_w, aw_w, off_w, proj_w, wcat, wproj);
  hipLaunchKernelGGL(k_proj,   dim3(6, 1024),  dim3(256), 0, stream,
                     x, wcat, v_b, aw_b, off_b, vbuf, awraw, offraw);
  hipLaunchKernelGGL(k_sample, dim3(65536),    dim3(256), 0, stream,
                     vbuf, awraw, offraw, attn);
  hipLaunchKernelGGL(k_out,    dim3(4, 1024),  dim3(256), 0, stream,
                     attn, wproj, proj_b, out);
}

// Round 3
// 258.653 us; speedup vs baseline: 1.3188x; 1.3188x over previous
//
#include <hip/hip_runtime.h>

// Problem constants: B=4, N_TOK=16384, DIM=256, NH=8, NP=4, HD=32, H=W=128.
// M = 65536 rows.

typedef __attribute__((ext_vector_type(8))) short bf16x8;
typedef __attribute__((ext_vector_type(4))) float f32x4;

__device__ __forceinline__ short f2bf(float f) {
  unsigned u = __float_as_uint(f);
  u = u + 0x7FFFu + ((u >> 16) & 1u);   // round-to-nearest-even
  return (short)(u >> 16);
}

__device__ __forceinline__ void gload16(const void* g, void* l) {
  __builtin_amdgcn_global_load_lds(
      (const __attribute__((address_space(1))) unsigned int*)g,
      (__attribute__((address_space(3))) unsigned int*)l, 16, 0, 0);
}

// ---------------------------------------------------------------- k_prep
// wcat[384][256] bf16 = concat(v_w[256], aw_w[32], off_w[64], zeros[32])
// wproj[256][256] bf16 = proj_w
__global__ __launch_bounds__(256) void k_prep(
    const float* __restrict__ v_w, const float* __restrict__ aw_w,
    const float* __restrict__ off_w, const float* __restrict__ proj_w,
    short* __restrict__ wcat, short* __restrict__ wproj)
{
  int idx = blockIdx.x * 256 + threadIdx.x;   // grid 640 -> idx < 163840
  if (idx < 384 * 256) {
    int row = idx >> 8;
    float val = 0.f;
    if (row < 256)      val = v_w[idx];
    else if (row < 288) val = aw_w[idx - 256 * 256];
    else if (row < 352) val = off_w[idx - 288 * 256];
    wcat[idx] = f2bf(val);
  } else {
    int j = idx - 384 * 256;                  // < 65536
    wproj[j] = f2bf(proj_w[j]);
  }
}

// ---------------------------------------------------------------- k_proj
// C[65536][384] = x @ wcat.T ; epilogue scatters v / aw / off.
// 128x128 tile, BK=64, 4 waves (2x2, each 64x64 = 4x4 frags of 16x16x32).
// B staged by global_load_lds w/ pre-swizzled source; A reg-staged (f32->bf16)
// with swizzled ds_write. LDS groups (16B) at slot  s = g ^ (row&7).
__global__ __launch_bounds__(256) void k_proj(
    const float* __restrict__ x, const short* __restrict__ wcat,
    const float* __restrict__ v_b, const float* __restrict__ aw_b,
    const float* __restrict__ off_b,
    float* __restrict__ vbuf,            // [32][16384][32] f32 (= d_out scratch)
    float* __restrict__ awraw,           // [32][16384][4]
    float* __restrict__ offraw)          // [32][16384][4][2]
{
  __shared__ short As[128 * 64];
  __shared__ short Bs[128 * 64];
  const int tid  = threadIdx.x;
  const int wave = tid >> 6, lane = tid & 63;
  const int c0   = blockIdx.x << 7;   // 0,128,256
  const int row0 = blockIdx.y << 7;

  // A staging: thread t handles row ar = t>>1, logical groups (t&1)*4..+3
  const int ar  = tid >> 1;
  const int acb = (tid & 1) << 5;     // float col base within BK (0 or 32)
  const float* xg = x + (size_t)(row0 + ar) * 256 + acb;

  const int wr = wave >> 1, wc = wave & 1;
  const int lr = lane & 15, kg = lane >> 4;

  f32x4 acc[4][4] = {};

  for (int kt = 0; kt < 4; ++kt) {
    // ---- B stage: 4 x global_load_lds per wave (16KB tile total)
#pragma unroll
    for (int i = 0; i < 4; ++i) {
      int fb = ((wave << 2) + i) << 6;        // flat group base (wave-uniform)
      int f  = fb + lane;
      int r  = f >> 3, s = f & 7;
      int g  = s ^ (r & 7);                   // inverse-swizzled source group
      const short* src = wcat + (size_t)(c0 + r) * 256 + (kt << 6) + (g << 3);
      gload16(src, &Bs[(size_t)fb << 3]);
    }
    // ---- A stage: 8 f32x4 loads -> cvt -> 4 swizzled ds_write_b128
    {
      const float* ap = xg + (kt << 6);
      f32x4 fv[8];
#pragma unroll
      for (int i = 0; i < 8; ++i) fv[i] = ((const f32x4*)ap)[i];
#pragma unroll
      for (int i = 0; i < 4; ++i) {
        bf16x8 v;
#pragma unroll
        for (int j = 0; j < 4; ++j) { v[j] = f2bf(fv[2*i][j]); v[4+j] = f2bf(fv[2*i+1][j]); }
        int g = ((tid & 1) << 2) + i;         // logical group 0..7
        int s = g ^ (ar & 7);
        *(bf16x8*)&As[(ar << 6) + (s << 3)] = v;
      }
    }
    __syncthreads();   // drains vmcnt (gload_lds) + lgkm (ds_write)

#pragma unroll
    for (int ks = 0; ks < 2; ++ks) {
      bf16x8 a[4], b[4];
#pragma unroll
      for (int m = 0; m < 4; ++m) {
        int r = (wr << 6) + (m << 4) + lr;
        int g = (ks << 2) + kg;
        a[m] = *(const bf16x8*)&As[(r << 6) + ((g ^ (r & 7)) << 3)];
      }
#pragma unroll
      for (int n = 0; n < 4; ++n) {
        int r = (wc << 6) + (n << 4) + lr;
        int g = (ks << 2) + kg;
        b[n] = *(const bf16x8*)&Bs[(r << 6) + ((g ^ (r & 7)) << 3)];
      }
#pragma unroll
      for (int m = 0; m < 4; ++m)
#pragma unroll
        for (int n = 0; n < 4; ++n)
          acc[m][n] = __builtin_amdgcn_mfma_f32_16x16x32_bf16(a[m], b[n], acc[m][n], 0, 0, 0);
    }
    __syncthreads();
  }

  // epilogue: C/D layout col=lane&15, row=(lane>>4)*4+reg  [m89-verified]
#pragma unroll
  for (int m = 0; m < 4; ++m) {
#pragma unroll
    for (int n = 0; n < 4; ++n) {
#pragma unroll
      for (int j = 0; j < 4; ++j) {
        int r = row0 + (wr << 6) + (m << 4) + ((lane >> 4) << 2) + j;
        int c = c0 + (wc << 6) + (n << 4) + lr;
        float v = acc[m][n][j];
        int b_ = r >> 14, nn = r & 16383;
        if (c < 256) {
          float val = v + v_b[c];
          int h = c >> 5, d = c & 31;
          vbuf[((((size_t)((b_ << 3) + h)) << 14) + nn) * 32 + d] = val;
        } else if (c < 288) {
          int q = c - 256;
          int h = q >> 2, p = q & 3;
          awraw[((((size_t)((b_ << 3) + h)) << 14) + nn) * 4 + p] = v + aw_b[q];
        } else if (c < 352) {
          int q = c - 288;
          int h = q >> 3, rest = q & 7;   // rest = p*2 + xy
          offraw[((((size_t)((b_ << 3) + h)) << 14) + nn) * 8 + rest] = v + off_b[q];
        } // c >= 352: padding, skip
      }
    }
  }
}

// ---------------------------------------------------------------- k_sample
// 8 lanes per (g,n) item; float4 gathers; fast softmax over 4 points.
__global__ __launch_bounds__(256) void k_sample(
    const float* __restrict__ vbuf, const float* __restrict__ awraw,
    const float* __restrict__ offraw, unsigned short* __restrict__ attn)
{
  const int tid  = threadIdx.x;
  const int item = (blockIdx.x << 5) + (tid >> 3);   // g*16384 + n
  const int q    = tid & 7;                          // float4 slot (d = 4q..4q+3)
  const int g = item >> 14, n = item & 16383;
  const float px = (float)(n & 127), py = (float)(n >> 7);

  f32x4 aw = *(const f32x4*)(awraw + (size_t)item * 4);
  const f32x4* opv = (const f32x4*)(offraw + (size_t)item * 8);
  f32x4 o0 = opv[0], o1 = opv[1];

  float mx = fmaxf(fmaxf(aw[0], aw[1]), fmaxf(aw[2], aw[3]));
  float e0 = __expf(aw[0] - mx), e1 = __expf(aw[1] - mx);
  float e2 = __expf(aw[2] - mx), e3 = __expf(aw[3] - mx);
  float inv = __fdividef(1.f, e0 + e1 + e2 + e3);
  float wts[4] = {e0 * inv, e1 * inv, e2 * inv, e3 * inv};
  float oxs[4] = {o0[0], o0[2], o1[0], o1[2]};
  float oys[4] = {o0[1], o0[3], o1[1], o1[3]};

  const float* vg = vbuf + (((size_t)g) << 19);      // g*16384*32
  f32x4 o = {0.f, 0.f, 0.f, 0.f};
#pragma unroll
  for (int p = 0; p < 4; ++p) {
    float gx = px + oxs[p], gy = py + oys[p];
    float x0f = floorf(gx), y0f = floorf(gy);
    float wx1 = gx - x0f, wx0 = 1.f - wx1;
    float wy1 = gy - y0f, wy0 = 1.f - wy1;
    int x0 = (int)x0f, y0 = (int)y0f;
    const float* base = vg + (((y0 << 7) + x0) << 5) + (q << 2);
    bool xv0 = (unsigned)x0 < 128u, xv1 = (unsigned)(x0 + 1) < 128u;
    bool yv0 = (unsigned)y0 < 128u, yv1 = (unsigned)(y0 + 1) < 128u;
    f32x4 c00 = {0,0,0,0}, c10 = {0,0,0,0}, c01 = {0,0,0,0}, c11 = {0,0,0,0};
    if (xv0 & yv0) c00 = *(const f32x4*)(base);
    if (xv1 & yv0) c10 = *(const f32x4*)(base + 32);
    if (xv0 & yv1) c01 = *(const f32x4*)(base + 4096);
    if (xv1 & yv1) c11 = *(const f32x4*)(base + 4128);
    float w00 = wts[p] * (wy0 * wx0), w10 = wts[p] * (wy0 * wx1);
    float w01 = wts[p] * (wy1 * wx0), w11 = wts[p] * (wy1 * wx1);
    o += w00 * c00 + w10 * c10 + w01 * c01 + w11 * c11;
  }
  int b_ = g >> 3, h = g & 7;
  union { unsigned long long u64; unsigned short us[4]; } pk;
#pragma unroll
  for (int j = 0; j < 4; ++j) pk.us[j] = (unsigned short)f2bf(o[j]);
  *(unsigned long long*)(attn + ((((size_t)b_ << 14) + n) << 8) + (h << 5) + (q << 2)) = pk.u64;
}

// ---------------------------------------------------------------- k_out
// out[65536][256] = attn @ proj_w.T + proj_b   (f32 output)
// Same 128x128/BK=64 structure; BOTH operands via global_load_lds.
__global__ __launch_bounds__(256) void k_out(
    const unsigned short* __restrict__ attn, const short* __restrict__ wproj,
    const float* __restrict__ proj_b, float* __restrict__ out)
{
  __shared__ short As[128 * 64];
  __shared__ short Bs[128 * 64];
  const int tid  = threadIdx.x;
  const int wave = tid >> 6, lane = tid & 63;
  const int c0   = blockIdx.x << 7;   // 0,128
  const int row0 = blockIdx.y << 7;

  const int wr = wave >> 1, wc = wave & 1;
  const int lr = lane & 15, kg = lane >> 4;

  f32x4 acc[4][4] = {};

  for (int kt = 0; kt < 4; ++kt) {
#pragma unroll
    for (int i = 0; i < 4; ++i) {
      int fb = ((wave << 2) + i) << 6;
      int f  = fb + lane;
      int r  = f >> 3, s = f & 7;
      int g  = s ^ (r & 7);
      const short* srcA = (const short*)attn + (size_t)(row0 + r) * 256 + (kt << 6) + (g << 3);
      const short* srcB = wproj + (size_t)(c0 + r) * 256 + (kt << 6) + (g << 3);
      gload16(srcA, &As[(size_t)fb << 3]);
      gload16(srcB, &Bs[(size_t)fb << 3]);
    }
    __syncthreads();

#pragma unroll
    for (int ks = 0; ks < 2; ++ks) {
      bf16x8 a[4], b[4];
#pragma unroll
      for (int m = 0; m < 4; ++m) {
        int r = (wr << 6) + (m << 4) + lr;
        int g = (ks << 2) + kg;
        a[m] = *(const bf16x8*)&As[(r << 6) + ((g ^ (r & 7)) << 3)];
      }
#pragma unroll
      for (int n = 0; n < 4; ++n) {
        int r = (wc << 6) + (n << 4) + lr;
        int g = (ks << 2) + kg;
        b[n] = *(const bf16x8*)&Bs[(r << 6) + ((g ^ (r & 7)) << 3)];
      }
#pragma unroll
      for (int m = 0; m < 4; ++m)
#pragma unroll
        for (int n = 0; n < 4; ++n)
          acc[m][n] = __builtin_amdgcn_mfma_f32_16x16x32_bf16(a[m], b[n], acc[m][n], 0, 0, 0);
    }
    __syncthreads();
  }

#pragma unroll
  for (int m = 0; m < 4; ++m) {
#pragma unroll
    for (int n = 0; n < 4; ++n) {
#pragma unroll
      for (int j = 0; j < 4; ++j) {
        int r = row0 + (wr << 6) + (m << 4) + ((lane >> 4) << 2) + j;
        int c = c0 + (wc << 6) + (n << 4) + lr;
        out[(size_t)r * 256 + c] = acc[m][n][j] + proj_b[c];
      }
    }
  }
}

// ---------------------------------------------------------------- launch
extern "C" void kernel_launch(void* const* d_in, const int* in_sizes, int n_in,
                              void* d_out, int out_size, void* d_ws, size_t ws_size,
                              hipStream_t stream)
{
  const float* x      = (const float*)d_in[0];
  const float* v_w    = (const float*)d_in[1];
  const float* v_b    = (const float*)d_in[2];
  const float* aw_w   = (const float*)d_in[3];
  const float* aw_b   = (const float*)d_in[4];
  const float* off_w  = (const float*)d_in[5];
  const float* off_b  = (const float*)d_in[6];
  const float* proj_w = (const float*)d_in[7];
  const float* proj_b = (const float*)d_in[8];
  float* out = (float*)d_out;

  char* ws = (char*)d_ws;
  short* wcat   = (short*)(ws + 0);               // 196,608 B
  short* wproj  = (short*)(ws + 262144);          // 131,072 B
  float* awraw  = (float*)(ws + 1048576);         // 8,388,608 B
  float* offraw = (float*)(ws + 9437184);         // 16,777,216 B
  unsigned short* attn = (unsigned short*)(ws + 26214400);  // 33,554,432 B
  float* vbuf = (float*)d_out;  // reuse d_out (64MB) as f32 v maps (exactly 64MB)

  hipLaunchKernelGGL(k_prep,   dim3(640),      dim3(256), 0, stream,
                     v_w, aw_w, off_w, proj_w, wcat, wproj);
  hipLaunchKernelGGL(k_proj,   dim3(3, 512),   dim3(256), 0, stream,
                     x, wcat, v_b, aw_b, off_b, vbuf, awraw, offraw);
  hipLaunchKernelGGL(k_sample, dim3(16384),    dim3(256), 0, stream,
                     vbuf, awraw, offraw, attn);
  hipLaunchKernelGGL(k_out,    dim3(2, 512),   dim3(256), 0, stream,
                     attn, wproj, proj_b, out);
}